// Round 7
// baseline (531.733 us; speedup 1.0000x reference)
//
#include <hip/hip_runtime.h>
#include <hip/hip_bf16.h>
#include <stdint.h>

typedef float f32x4 __attribute__((ext_vector_type(4)));
typedef short s16x8 __attribute__((ext_vector_type(8)));
typedef short s16x4 __attribute__((ext_vector_type(4)));

__device__ __forceinline__ f32x4 mfma16(s16x8 a, s16x8 b, f32x4 c) {
  return __builtin_amdgcn_mfma_f32_16x16x32_bf16(a, b, c, 0, 0, 0);
}

typedef __attribute__((address_space(3))) void lds_void;
typedef const __attribute__((address_space(1))) void gbl_void;

__device__ __forceinline__ void gload_lds16(const void* g, void* l) {
  __builtin_amdgcn_global_load_lds((gbl_void*)g, (lds_void*)l, 16, 0, 0);
}

__device__ __forceinline__ short f2bf(float f) {
  uint32_t u = __builtin_bit_cast(uint32_t, f);
  u += 0x7fffu + ((u >> 16) & 1u);
  return (short)(u >> 16);
}

// ---------------------------------------------------------------------------
// x f32 -> bf16, 4 elems/thread
__global__ __launch_bounds__(256) void k_cvt_x(const float* __restrict__ in,
                                               short* __restrict__ out) {
  const int i = blockIdx.x * 256 + threadIdx.x;
  const f32x4 v = ((const f32x4*)in)[i];
  s16x4 o;
  o[0] = f2bf(v[0]); o[1] = f2bf(v[1]); o[2] = f2bf(v[2]); o[3] = f2bf(v[3]);
  ((s16x4*)out)[i] = o;
}

// W[K][N] f32 -> Wt[N][K] bf16 (B^T layout for the GEMM)
__global__ __launch_bounds__(256) void k_transpose_w(const float* __restrict__ W,
                                                     short* __restrict__ Wt,
                                                     int K, int N) {
  __shared__ float tile[32][33];
  const int nb = blockIdx.x * 32;
  const int kb = blockIdx.y * 32;
  const int tx = threadIdx.x & 31;
  const int ty = threadIdx.x >> 5;  // 0..7
#pragma unroll
  for (int r = 0; r < 4; ++r)
    tile[ty + 8 * r][tx] = W[(size_t)(kb + ty + 8 * r) * N + nb + tx];
  __syncthreads();
#pragma unroll
  for (int r = 0; r < 4; ++r)
    Wt[(size_t)(nb + ty + 8 * r) * K + kb + tx] = f2bf(tile[tx][ty + 8 * r]);
}

// ---------------------------------------------------------------------------
// Proj mainloop (unchanged, verified): C[128x128] = A[128x512] * B^T[128x512]^T.
// T3-minimum pipeline, 2 LDS slots, one barrier per K-tile.
__device__ __forceinline__ void gemm_mainloop_512(const short* __restrict__ Ag,
                                                  const short* __restrict__ Bg,
                                                  f32x4 acc[4][4]) {
  __shared__ char smem[65536];
  const int t = threadIdx.x;
  const int lane = t & 63;
  const int wv = t >> 6;
  const int lg = lane >> 4;
  const int l15 = lane & 15;
  const int wr = wv >> 1;
  const int wc = wv & 1;

#define STAGE_TILE(slot, kt)                                                  \
  {                                                                           \
    char* base_ = smem + (slot) * 32768;                                      \
    _Pragma("unroll") for (int i_ = 0; i_ < 4; ++i_) {                        \
      const int p_ = (i_ * 256 + t) * 16;                                     \
      const int row_ = p_ >> 7;                                               \
      const int kb_ = (p_ & 127) ^ ((row_ & 7) << 4);                         \
      gload_lds16((const char*)Ag + (size_t)row_ * 1024 + (kt) * 128 + kb_,   \
                  base_ + i_ * 4096 + wv * 1024);                             \
      gload_lds16((const char*)Bg + (size_t)row_ * 1024 + (kt) * 128 + kb_,   \
                  base_ + 16384 + i_ * 4096 + wv * 1024);                     \
    }                                                                         \
  }

  STAGE_TILE(0, 0);
  __syncthreads();

  for (int kt = 0; kt < 8; ++kt) {
    const int s = kt & 1;
    if (kt < 7) STAGE_TILE(s ^ 1, kt + 1);
    const char* As = smem + s * 32768;
    const char* Bs = As + 16384;
#pragma unroll
    for (int ks = 0; ks < 2; ++ks) {
      s16x8 a[4], b[4];
#pragma unroll
      for (int f = 0; f < 4; ++f) {
        const int ra = wr * 64 + f * 16 + l15;
        a[f] = *(const s16x8*)(As + ra * 128 +
                               ((ks * 64 + lg * 16) ^ ((ra & 7) << 4)));
      }
#pragma unroll
      for (int f = 0; f < 4; ++f) {
        const int rb = wc * 64 + f * 16 + l15;
        b[f] = *(const s16x8*)(Bs + rb * 128 +
                               ((ks * 64 + lg * 16) ^ ((rb & 7) << 4)));
      }
#pragma unroll
      for (int fm = 0; fm < 4; ++fm)
#pragma unroll
        for (int fn = 0; fn < 4; ++fn)
          acc[fm][fn] = mfma16(a[fm], b[fn], acc[fm][fn]);
    }
    __syncthreads();
  }
#undef STAGE_TILE
}

// ---------------------------------------------------------------------------
// FUSED QKV projection + attention. One block per (bm: 128 rows = 2 windows,
// head h). GEMM x[128x512] @ Wt[96 rows][512] -> Q|K|V [128x32] each, bias
// added, staged to LDS as bf16; then per-window S=scale*QK^T+mask, softmax,
// O=PV, written straight to AO. Kills the Q/K/V HBM round-trip (384 MB).
// XCD swizzle: 16 heads of one bm contiguous on one XCD (x + mask L2-hit).
__global__ __launch_bounds__(256) void k_qkv_attn(
    const short* __restrict__ xb, const short* __restrict__ Wqt,
    const short* __restrict__ Wkvt, const float* __restrict__ bq,
    const float* __restrict__ bkv, const float* __restrict__ mask,
    short* __restrict__ AO) {
  __shared__ char smem[57344];  // mainloop: 2 slots x (A 16KB + B 12KB)
  const int bid = blockIdx.x;                      // 0..8191
  const int orig = (bid & 7) * 1024 + (bid >> 3);  // bijective, 8192 = 8*1024
  const int bm = orig >> 4;                        // 0..511
  const int h = orig & 15;                         // 0..15
  const int t = threadIdx.x, lane = t & 63, wv = t >> 6;
  const int lg = lane >> 4, l15 = lane & 15;
  const int wr = wv >> 1, wc = wv & 1;

  const short* Ag = xb + (size_t)bm * 128 * 512;

  f32x4 acc[4][3];
  const f32x4 z = {0.f, 0.f, 0.f, 0.f};
#pragma unroll
  for (int i = 0; i < 4; ++i)
#pragma unroll
    for (int j = 0; j < 3; ++j) acc[i][j] = z;

  // ---- GEMM mainloop: B rows 0..31=Q(Wqt h), 32..63=K(Wkvt h), 64..95=V ----
#define STAGE_QKV(slot, kt)                                                   \
  {                                                                           \
    char* base_ = smem + (slot) * 28672;                                      \
    _Pragma("unroll") for (int i_ = 0; i_ < 4; ++i_) {                        \
      const int p_ = (i_ * 256 + t) * 16;                                     \
      const int row_ = p_ >> 7;                                               \
      const int kb_ = (p_ & 127) ^ ((row_ & 7) << 4);                         \
      gload_lds16((const char*)Ag + (size_t)row_ * 1024 + (kt) * 128 + kb_,   \
                  base_ + i_ * 4096 + wv * 1024);                             \
    }                                                                         \
    _Pragma("unroll") for (int i_ = 0; i_ < 3; ++i_) {                        \
      const int p_ = (i_ * 256 + t) * 16;                                     \
      const int row_ = p_ >> 7;        /* 0..95; i_=0:Q 1:K 2:V (uniform) */  \
      const int ra_ = row_ - i_ * 32;  /* 0..31 within group */               \
      const int kb_ = (p_ & 127) ^ ((row_ & 7) << 4);                         \
      const short* br_ = (i_ == 0) ? Wqt + (size_t)(h * 32 + ra_) * 512       \
                       : (i_ == 1) ? Wkvt + (size_t)(h * 32 + ra_) * 512      \
                                   : Wkvt + (size_t)(512 + h * 32 + ra_) * 512;\
      gload_lds16((const char*)br_ + (kt) * 128 + kb_,                        \
                  base_ + 16384 + i_ * 4096 + wv * 1024);                     \
    }                                                                         \
  }

  STAGE_QKV(0, 0);
  __syncthreads();
  for (int kt = 0; kt < 8; ++kt) {
    const int s = kt & 1;
    if (kt < 7) STAGE_QKV(s ^ 1, kt + 1);
    const char* As = smem + s * 28672;
    const char* Bs = As + 16384;
#pragma unroll
    for (int ks = 0; ks < 2; ++ks) {
      s16x8 a[4], b[3];
#pragma unroll
      for (int f = 0; f < 4; ++f) {
        const int ra = wr * 64 + f * 16 + l15;
        a[f] = *(const s16x8*)(As + ra * 128 +
                               ((ks * 64 + lg * 16) ^ ((ra & 7) << 4)));
      }
#pragma unroll
      for (int f = 0; f < 3; ++f) {
        const int rb = wc * 48 + f * 16 + l15;
        b[f] = *(const s16x8*)(Bs + rb * 128 +
                               ((ks * 64 + lg * 16) ^ ((rb & 7) << 4)));
      }
#pragma unroll
      for (int fm = 0; fm < 4; ++fm)
#pragma unroll
        for (int fn = 0; fn < 3; ++fn)
          acc[fm][fn] = mfma16(a[fm], b[fn], acc[fm][fn]);
    }
    __syncthreads();  // also retires prefetch (vmcnt drained before barrier)
  }
#undef STAGE_QKV

  // ---- Epilogue: bias + scatter Q/K/V^T to LDS (bf16, swizzled) ----
  // Qs/Ks [128 rows][32 cols]: byte = m*64 + ((c>>3)^((m>>1)&3))*16 + (c&7)*2
  // Vt [2 win][32 d][64 m]:    byte = w*4096 + d*128 + ((2m)^((d&7)<<4))
  char* Qs = smem;            // 8 KB
  char* Ks = smem + 8192;     // 8 KB
  char* Vt = smem + 16384;    // 8 KB
  char* Pb = smem + 24576;    // 16 KB (4 waves x [32][64] bf16)
#pragma unroll
  for (int fm = 0; fm < 4; ++fm)
#pragma unroll
    for (int fn = 0; fn < 3; ++fn)
#pragma unroll
      for (int j = 0; j < 4; ++j) {
        const int m = wr * 64 + fm * 16 + lg * 4 + j;  // 0..127
        const int c = wc * 48 + fn * 16 + l15;         // 0..95 (uniform group)
        float v = acc[fm][fn][j];
        if (c < 32) {
          v += bq[h * 32 + c];
          *(short*)(Qs + m * 64 + (((c >> 3) ^ ((m >> 1) & 3)) << 4) +
                    ((c & 7) * 2)) = f2bf(v);
        } else if (c < 64) {
          const int cc = c - 32;
          v += bkv[h * 32 + cc];
          *(short*)(Ks + m * 64 + (((cc >> 3) ^ ((m >> 1) & 3)) << 4) +
                    ((cc & 7) * 2)) = f2bf(v);
        } else {
          const int cc = c - 64;
          v += bkv[512 + h * 32 + cc];
          *(short*)(Vt + (m >> 6) * 4096 + cc * 128 +
                    (((m & 63) * 2) ^ ((cc & 7) << 4))) = f2bf(v);
        }
      }
  __syncthreads();

  // ---- Attention: wave wv -> window wi = wv>>1, row-half rh = wv&1 ----
  const int wi = wv >> 1, rh = wv & 1;
  const float* mrow = mask + (size_t)((2 * bm + wi) & 255) * 4096;

  // S = Q K^T  (D=32 = exactly one MFMA k-step)
  s16x8 qa[2];
#pragma unroll
  for (int fm = 0; fm < 2; ++fm) {
    const int qr = wi * 64 + rh * 32 + fm * 16 + l15;
    qa[fm] = *(const s16x8*)(Qs + qr * 64 + ((lg ^ ((qr >> 1) & 3)) << 4));
  }
  f32x4 sacc[2][4];
#pragma unroll
  for (int fn = 0; fn < 4; ++fn) {
    const int kr = wi * 64 + fn * 16 + l15;
    const s16x8 kf =
        *(const s16x8*)(Ks + kr * 64 + ((lg ^ ((kr >> 1) & 3)) << 4));
#pragma unroll
    for (int fm = 0; fm < 2; ++fm) sacc[fm][fn] = mfma16(qa[fm], kf, z);
  }

  // softmax over 64 cols (wave-parallel, 16-lane shuffle reduce)
  const float scale = 0.17677669529663687f;  // 1/sqrt(32)
  float sv[2][4][4];
#pragma unroll
  for (int fm = 0; fm < 2; ++fm)
#pragma unroll
    for (int fn = 0; fn < 4; ++fn)
#pragma unroll
      for (int j = 0; j < 4; ++j)
        sv[fm][fn][j] = sacc[fm][fn][j] * scale +
                        mrow[(rh * 32 + fm * 16 + lg * 4 + j) * 64 +
                             fn * 16 + l15];
#pragma unroll
  for (int fm = 0; fm < 2; ++fm)
#pragma unroll
    for (int j = 0; j < 4; ++j) {
      float mx = fmaxf(fmaxf(sv[fm][0][j], sv[fm][1][j]),
                       fmaxf(sv[fm][2][j], sv[fm][3][j]));
#pragma unroll
      for (int off = 1; off < 16; off <<= 1) mx = fmaxf(mx, __shfl_xor(mx, off));
      float sum = 0.f;
#pragma unroll
      for (int fn = 0; fn < 4; ++fn) {
        sv[fm][fn][j] = __expf(sv[fm][fn][j] - mx);
        sum += sv[fm][fn][j];
      }
#pragma unroll
      for (int off = 1; off < 16; off <<= 1) sum += __shfl_xor(sum, off);
      const float inv = 1.f / sum;
#pragma unroll
      for (int fn = 0; fn < 4; ++fn) sv[fm][fn][j] *= inv;
    }

  // P -> wave-private LDS (bf16, swizzled); no barrier needed (same-wave RW)
  char* pw = Pb + wv * 4096;
#pragma unroll
  for (int fm = 0; fm < 2; ++fm)
#pragma unroll
    for (int fn = 0; fn < 4; ++fn)
#pragma unroll
      for (int j = 0; j < 4; ++j) {
        const int prow = fm * 16 + lg * 4 + j;   // 0..31
        const int pcol = fn * 16 + l15;
        *(short*)(pw + prow * 128 + ((pcol * 2) ^ ((prow & 7) << 4))) =
            f2bf(sv[fm][fn][j]);
      }

  // O = P @ V : K=64 -> 2 k-steps; per wave 32 rows x 32 d
  f32x4 od[2][2];
  od[0][0] = z; od[0][1] = z; od[1][0] = z; od[1][1] = z;
#pragma unroll
  for (int ks = 0; ks < 2; ++ks) {
#pragma unroll
    for (int fm = 0; fm < 2; ++fm) {
      const s16x8 pa = *(const s16x8*)(pw + (fm * 16 + l15) * 128 +
                                       ((ks * 64 + lg * 16) ^ ((l15 & 7) << 4)));
#pragma unroll
      for (int fd = 0; fd < 2; ++fd) {
        const int d = fd * 16 + l15;
        const s16x8 vb = *(const s16x8*)(Vt + wi * 4096 + d * 128 +
                                         ((ks * 64 + lg * 16) ^ ((d & 7) << 4)));
        od[fm][fd] = mfma16(pa, vb, od[fm][fd]);
      }
    }
  }

  // AO[bm*128 + wi*64 + rh*32 + row][h*32 + d] bf16
#pragma unroll
  for (int fm = 0; fm < 2; ++fm)
#pragma unroll
    for (int fd = 0; fd < 2; ++fd)
#pragma unroll
      for (int j = 0; j < 4; ++j) {
        const int row = bm * 128 + wi * 64 + rh * 32 + fm * 16 + lg * 4 + j;
        const int col = h * 32 + fd * 16 + l15;
        AO[(size_t)row * 512 + col] = f2bf(od[fm][fd][j]);
      }
}

// ---------------------------------------------------------------------------
// Output projection: out[m][n] = AO[m][:] . Wp[:][n] + bp[n], f32 out.
// Linear grid 2048 with XCD-chunk swizzle: 4 bn-blocks of one bm per XCD.
__global__ __launch_bounds__(256) void k_gemm_proj(
    const short* __restrict__ AO, const short* __restrict__ Wpt,
    const float* __restrict__ bp, float* __restrict__ out) {
  const int bid = blockIdx.x;                 // 0..2047
  const int orig = (bid & 7) * 256 + (bid >> 3);  // chunk of 256 per XCD
  const int bm = orig >> 2;                   // 0..511
  const int bn = orig & 3;                    // 0..3
  f32x4 acc[4][4];
  const f32x4 z = {0.f, 0.f, 0.f, 0.f};
  for (int i = 0; i < 4; ++i)
    for (int j = 0; j < 4; ++j) acc[i][j] = z;

  gemm_mainloop_512(AO + (size_t)bm * 65536, Wpt + (size_t)bn * 65536, acc);

  const int t = threadIdx.x, lane = t & 63, wv = t >> 6;
  const int lg = lane >> 4, l15 = lane & 15;
  const int wr = wv >> 1, wc = wv & 1;
  const int m0 = bm * 128 + wr * 64;
  const int n0 = bn * 128 + wc * 64;
#pragma unroll
  for (int fm = 0; fm < 4; ++fm)
#pragma unroll
    for (int fn = 0; fn < 4; ++fn)
#pragma unroll
      for (int j = 0; j < 4; ++j) {
        const int m = m0 + fm * 16 + lg * 4 + j;
        const int n = n0 + fn * 16 + l15;
        out[(size_t)m * 512 + n] = acc[fm][fn][j] + bp[n];
      }
}

// ---------------------------------------------------------------------------
extern "C" void kernel_launch(void* const* d_in, const int* in_sizes, int n_in,
                              void* d_out, int out_size, void* d_ws,
                              size_t ws_size, hipStream_t stream) {
  const float* x    = (const float*)d_in[0];
  const float* mask = (const float*)d_in[1];
  const float* Wq   = (const float*)d_in[2];
  const float* bq   = (const float*)d_in[3];
  const float* Wkv  = (const float*)d_in[4];
  const float* bkv  = (const float*)d_in[5];
  const float* Wp   = (const float*)d_in[6];
  const float* bp   = (const float*)d_in[7];
  float* out = (float*)d_out;
  char* ws = (char*)d_ws;

  // workspace layout (bytes); AO must NOT alias xb (xb live in fused kernel)
  short* xb   = (short*)(ws);                       // 64 MB
  short* Wqt  = (short*)(ws + 67108864);            // 0.5 MB
  short* Wkvt = (short*)(ws + 67108864 + 524288);   // 1 MB
  short* Wpt  = (short*)(ws + 67108864 + 1572864);  // 0.5 MB
  short* AO   = (short*)(ws + 69206016);            // 64 MB

  k_cvt_x<<<dim3(32768), dim3(256), 0, stream>>>(x, xb);
  k_transpose_w<<<dim3(16, 16), dim3(256), 0, stream>>>(Wq, Wqt, 512, 512);
  k_transpose_w<<<dim3(32, 16), dim3(256), 0, stream>>>(Wkv, Wkvt, 512, 1024);
  k_transpose_w<<<dim3(16, 16), dim3(256), 0, stream>>>(Wp, Wpt, 512, 512);
  k_qkv_attn<<<dim3(8192), dim3(256), 0, stream>>>(xb, Wqt, Wkvt, bq, bkv,
                                                   mask, AO);
  k_gemm_proj<<<dim3(2048), dim3(256), 0, stream>>>(AO, Wpt, bp, out);
}